// Round 3
// baseline (195.201 us; speedup 1.0000x reference)
//
#include <hip/hip_runtime.h>
#include <hip/hip_bf16.h>

#define N_NODES 50000
#define N_EDGES 800000
#define D 128

#define NBUCK 3125       // bucket = dst>>4 (16 nodes); 50000 = 3125*16 exactly
#define BCAP  512        // slots/bucket; count ~256 +/- ~16 (sd); 16-sd margin

#define CONV_BLOCKS 3200 // 819200 threads; edges: first 200000 threads x4

using bf16x8 = __attribute__((ext_vector_type(8))) short;   // 8 bf16 (4 VGPRs)
using u16x8  = __attribute__((ext_vector_type(8))) unsigned short;
using f32x4  = __attribute__((ext_vector_type(4))) float;   // MFMA C/D

static __device__ __forceinline__ ushort f2bf(float f) {
    __hip_bfloat16 h = __float2bfloat16(f);   // RNE
    return *reinterpret_cast<ushort*>(&h);
}
static __device__ __forceinline__ float bf2f(ushort u) {
    return __uint_as_float(((unsigned)u) << 16);
}

// ---------------------------------------------------------------------------
// ws layout (~19.3 MB): bcnt[NBUCK], pairs[NBUCK*BCAP] int, xb (bf16 x),
// wb (bf16 W chunk-major, 32 KB). Scatter uses direct global atomics:
// 3125 counters x ~256 increments each -> negligible contention at LLC.
// ---------------------------------------------------------------------------

// Fused, sync-free: W->bf16 + edge scatter (global atomics) + x->bf16.
__global__ void __launch_bounds__(256)
convert_scatter(const float4* __restrict__ x4, ushort* __restrict__ xb,
                const float* __restrict__ W, ushort* __restrict__ wb,
                const int* __restrict__ src, const int* __restrict__ dst,
                int* __restrict__ bcnt, int* __restrict__ pairs) {
    const int gt = blockIdx.x * 256 + threadIdx.x;

    // W -> bf16 chunk-major [k/8][o][8] (first 2048 threads)
    if (gt < 2048) {
        int o  = gt & 127;
        int kc = gt >> 7;
        const float4* wp = (const float4*)(W + (size_t)o * D + kc * 8);
        float4 w0 = wp[0], w1 = wp[1];
        bf16x8 hv;
        hv[0] = (short)f2bf(w0.x); hv[1] = (short)f2bf(w0.y);
        hv[2] = (short)f2bf(w0.z); hv[3] = (short)f2bf(w0.w);
        hv[4] = (short)f2bf(w1.x); hv[5] = (short)f2bf(w1.y);
        hv[6] = (short)f2bf(w1.z); hv[7] = (short)f2bf(w1.w);
        *(bf16x8*)&wb[gt * 8] = hv;
    }

    // edge scatter: 4 edges/thread via int4, direct global atomicAdd
    if (gt < N_EDGES / 4) {
        int4 s = ((const int4*)src)[gt];
        int4 d = ((const int4*)dst)[gt];
#pragma unroll
        for (int e = 0; e < 4; ++e) {
            int sv = (e == 0) ? s.x : (e == 1) ? s.y : (e == 2) ? s.z : s.w;
            int dv = (e == 0) ? d.x : (e == 1) ? d.y : (e == 2) ? d.z : d.w;
            int bkt = dv >> 4;
            int pos = atomicAdd(&bcnt[bkt], 1);
            if (pos < BCAP)                       // ~16-sd guard, never trips
                pairs[bkt * BCAP + pos] = sv | ((dv & 15) << 16);
        }
    }

    // streaming conversion: 1.6M float4, <=2 iterations/thread
    const int total4 = N_NODES * D / 4;
    const int stride = CONV_BLOCKS * 256;
    for (int j = gt; j < total4; j += stride) {
        float4 v = x4[j];
        ushort4 u = make_ushort4(f2bf(v.x), f2bf(v.y), f2bf(v.z), f2bf(v.w));
        *(ushort4*)(xb + (size_t)j * 4) = u;
    }
}

// ---------------------------------------------------------------------------
// Fused per-bucket kernel: CSR-in-LDS (pairs read once into regs) -> gather
// to LDS agg tile -> MFMA GEMM + relu + residual. One block per 16-node
// bucket, 256 threads (4 waves). LDS 14016 B => 8 blocks/CU (32 waves/CU).
// B-fragments from global wb (32 KB, L1-resident).
// ---------------------------------------------------------------------------
__global__ void __launch_bounds__(256)
csr_gather_gemm(const int* __restrict__ pairs, const int* __restrict__ bcnt,
                const ushort* __restrict__ xb, const ushort* __restrict__ wb,
                float* __restrict__ out) {
    __shared__ __align__(16) char lds[14016];
    ushort* lsrc  = (ushort*)lds;                    //  1024 B
    ushort* aggL  = (ushort*)(lds + 1024);           //  4352 B
    float*  Ew    = (float*)(lds + 5376);            //  8448 B
    int*    lcnt2 = (int*)(lds + 13824);
    int*    lcur  = (int*)(lds + 13888);
    int*    lbeg  = (int*)(lds + 13952);

    const int b    = blockIdx.x;
    const int tid  = threadIdx.x;
    const int lane = tid & 63;
    const int wv   = tid >> 6;
    const int m16  = lane & 15;
    const int q    = lane >> 4;

    // ---- CSR in LDS: pairs -> regs, histogram -> 16-lane scan -> place ----
    const int base = b * BCAP;
    int n = bcnt[b];
    if (n > BCAP) n = BCAP;                          // 16-sd guard, never trips
    int p0 = -1, p1 = -1;
    if (tid < n)       p0 = pairs[base + tid];
    if (tid + 256 < n) p1 = pairs[base + 256 + tid];
    if (tid < 16) lcnt2[tid] = 0;
    __syncthreads();
    if (p0 >= 0) atomicAdd(&lcnt2[p0 >> 16], 1);
    if (p1 >= 0) atomicAdd(&lcnt2[p1 >> 16], 1);
    __syncthreads();
    if (tid < 16) {                       // wave 0: 16-lane inclusive shfl scan
        int v = lcnt2[tid];
        int incl = v;
#pragma unroll
        for (int o = 1; o < 16; o <<= 1) {
            int t = __shfl_up(incl, o, 64);
            if (tid >= o) incl += t;
        }
        lbeg[tid] = incl - v;
        lcur[tid] = incl - v;
    }
    __syncthreads();
    if (p0 >= 0) {
        int pos = atomicAdd(&lcur[p0 >> 16], 1);
        lsrc[pos] = (ushort)(p0 & 0xFFFF);
    }
    if (p1 >= 0) {
        int pos = atomicAdd(&lcur[p1 >> 16], 1);
        lsrc[pos] = (ushort)(p1 & 0xFFFF);
    }
    __syncthreads();                      // lcur[t] == end(t) now

    // ---- gather: wave wv owns nodes wv*4 .. wv*4+3 (sequential) ----
    // Quarter-wave rows: 16 lanes x u16x8 (16B) = one full 256B bf16 row;
    // 4 rows/step. Mean degree 16 => ~4 steps/node.
    const int c8 = m16 << 3;               // bf16 col 0,8,..,120
    const ushort* xbb = xb + c8;
#pragma unroll 1
    for (int m = 0; m < 4; ++m) {
        const int nloc = wv * 4 + m;
        const int beg = lbeg[nloc], end = lcur[nloc];
        float acc[8];
#pragma unroll
        for (int j = 0; j < 8; ++j) acc[j] = 0.f;

        int t = beg;
        for (; t + 16 <= end; t += 16) {   // 16 rows in flight
            int s0 = lsrc[t + q];          // broadcast LDS read per quarter
            int s1 = lsrc[t + 4 + q];
            int s2 = lsrc[t + 8 + q];
            int s3 = lsrc[t + 12 + q];
            u16x8 u0 = *(const u16x8*)(xbb + (size_t)s0 * D);
            u16x8 u1 = *(const u16x8*)(xbb + (size_t)s1 * D);
            u16x8 u2 = *(const u16x8*)(xbb + (size_t)s2 * D);
            u16x8 u3 = *(const u16x8*)(xbb + (size_t)s3 * D);
#pragma unroll
            for (int j = 0; j < 8; ++j)
                acc[j] += (bf2f(u0[j]) + bf2f(u1[j])) + (bf2f(u2[j]) + bf2f(u3[j]));
        }
        for (; t + 4 <= end; t += 4) {
            int s = lsrc[t + q];
            u16x8 u = *(const u16x8*)(xbb + (size_t)s * D);
#pragma unroll
            for (int j = 0; j < 8; ++j) acc[j] += bf2f(u[j]);
        }
        const int rem = end - t;
        if (rem && q < rem) {
            int s = lsrc[t + q];
            u16x8 u = *(const u16x8*)(xbb + (size_t)s * D);
#pragma unroll
            for (int j = 0; j < 8; ++j) acc[j] += bf2f(u[j]);
        }
#pragma unroll
        for (int j = 0; j < 8; ++j) {
            acc[j] += __shfl_xor(acc[j], 16, 64);
            acc[j] += __shfl_xor(acc[j], 32, 64);
        }
        if (q == 0) {                      // row write: 16 lanes x 16B, 256B
            u16x8 u;
#pragma unroll
            for (int j = 0; j < 8; ++j) u[j] = f2bf(acc[j]);
            *(u16x8*)&aggL[(size_t)nloc * 136 + c8] = u;   // 272B rows, 16B-aligned
        }
    }
    __syncthreads();                       // aggL complete

    // ---- MFMA GEMM: out[n][o] = relu(sum_k agg[n][k]*W[o][k]) + x[n][o] ----
    // All waves share the same 16 A-rows; wave wv computes cols wv*32..wv*32+31.
    bf16x8 a[4];
#pragma unroll
    for (int kb = 0; kb < 4; ++kb)
        a[kb] = *(const bf16x8*)&aggL[(size_t)m16 * 136 + kb * 32 + q * 8];

    f32x4 acc[2];
#pragma unroll
    for (int tt = 0; tt < 2; ++tt) {
        const int t = wv * 2 + tt;
        acc[tt] = (f32x4){0.f, 0.f, 0.f, 0.f};
#pragma unroll
        for (int kb = 0; kb < 4; ++kb) {
            bf16x8 bfr = *(const bf16x8*)&wb[(((kb * 4 + q) * 128) + t * 16 + m16) * 8];
            acc[tt] = __builtin_amdgcn_mfma_f32_16x16x32_bf16(a[kb], bfr, acc[tt], 0, 0, 0);
        }
    }

#pragma unroll
    for (int tt = 0; tt < 2; ++tt) {
        const int t = wv * 2 + tt;
#pragma unroll
        for (int r = 0; r < 4; ++r)
            Ew[(q * 4 + r) * 132 + t * 16 + m16] = acc[tt][r];
    }
    __syncthreads();                       // Ew complete (cross-wave cols)

    // ---- epilogue: relu + residual, 2 float4 per thread, coalesced ----
#pragma unroll
    for (int k = 0; k < 2; ++k) {
        int idx = tid + k * 256;
        int row = idx >> 5;                // 0..15
        int c4  = (idx & 31) << 2;         // f32 col 0,4,..,124
        int node = b * 16 + row;           // < 50000 always (3125*16 exact)
        float4 v  = *(const float4*)&Ew[row * 132 + c4];
        ushort4 xu = *(const ushort4*)(xb + (size_t)node * D + c4);
        float4 o;
        o.x = fmaxf(v.x, 0.f) + bf2f(xu.x);
        o.y = fmaxf(v.y, 0.f) + bf2f(xu.y);
        o.z = fmaxf(v.z, 0.f) + bf2f(xu.z);
        o.w = fmaxf(v.w, 0.f) + bf2f(xu.w);
        *(float4*)(out + (size_t)node * D + c4) = o;
    }
}

// ===================== minimal fallback (tiny ws; never expected) ==========
__global__ void zero_out(float4* __restrict__ p, int n4) {
    int i = blockIdx.x * 256 + threadIdx.x;
    if (i < n4) p[i] = make_float4(0.f, 0.f, 0.f, 0.f);
}
__global__ void scatter_edges(const float* __restrict__ x,
                              const int* __restrict__ src,
                              const int* __restrict__ dst,
                              float* __restrict__ agg) {
    long long tid = (long long)blockIdx.x * 256 + threadIdx.x;
    if (tid >= (long long)N_EDGES * 32) return;
    int edge = (int)(tid >> 5);
    int c    = ((int)tid & 31) << 2;
    const float4 v = *(const float4*)(x + (size_t)src[edge] * D + c);
    float* p = agg + (size_t)dst[edge] * D + c;
    unsafeAtomicAdd(p + 0, v.x);
    unsafeAtomicAdd(p + 1, v.y);
    unsafeAtomicAdd(p + 2, v.z);
    unsafeAtomicAdd(p + 3, v.w);
}
__global__ void __launch_bounds__(256)
gemm_relu_res_f32(float* data, const float* __restrict__ W,
                  const float* __restrict__ x) {
    __shared__ __align__(16) char lds[50176];
    ushort* Wl = (ushort*)lds;
    ushort* Al = (ushort*)(lds + 32768);
    const int tid  = threadIdx.x;
    const int lane = tid & 63;
    const int wv   = tid >> 6;
    const int m16  = lane & 15;
    const int q    = lane >> 4;
#pragma unroll
    for (int i = 0; i < 8; ++i) {
        int g  = tid + i * 256;
        int o  = g & 127;
        int kc = g >> 7;
        const float4* wp = (const float4*)(W + (size_t)o * D + kc * 8);
        float4 w0 = wp[0], w1 = wp[1];
        bf16x8 hv;
        hv[0] = (short)f2bf(w0.x); hv[1] = (short)f2bf(w0.y);
        hv[2] = (short)f2bf(w0.z); hv[3] = (short)f2bf(w0.w);
        hv[4] = (short)f2bf(w1.x); hv[5] = (short)f2bf(w1.y);
        hv[6] = (short)f2bf(w1.z); hv[7] = (short)f2bf(w1.w);
        *(bf16x8*)&Wl[g * 8] = hv;
    }
    __syncthreads();
    const int nb = blockIdx.x * 64 + wv * 16;
    ushort* Aw = &Al[wv * (16 * 136)];
#pragma unroll
    for (int m = 0; m < 16; ++m) {
        int node = nb + m;
        float2 v = make_float2(0.f, 0.f);
        if (node < N_NODES)
            v = *(const float2*)(data + (size_t)node * D + lane * 2);
        *(ushort2*)&Aw[m * 136 + lane * 2] = make_ushort2(f2bf(v.x), f2bf(v.y));
    }
    bf16x8 a[4];
#pragma unroll
    for (int kb = 0; kb < 4; ++kb)
        a[kb] = *(const bf16x8*)&Aw[m16 * 136 + kb * 32 + q * 8];
    f32x4 acc[8];
#pragma unroll
    for (int t = 0; t < 8; ++t) {
        acc[t] = (f32x4){0.f, 0.f, 0.f, 0.f};
#pragma unroll
        for (int kb = 0; kb < 4; ++kb) {
            bf16x8 bfr = *(const bf16x8*)&Wl[(((kb * 4 + q) * 128) + t * 16 + m16) * 8];
            acc[t] = __builtin_amdgcn_mfma_f32_16x16x32_bf16(a[kb], bfr, acc[t], 0, 0, 0);
        }
    }
    __syncthreads();
    float* Ew = (float*)(lds + wv * 8448);
#pragma unroll
    for (int t = 0; t < 8; ++t)
#pragma unroll
        for (int r = 0; r < 4; ++r)
            Ew[(q * 4 + r) * 132 + t * 16 + m16] = acc[t][r];
    const int h  = lane >> 5;
    const int c4 = (lane & 31) << 2;
#pragma unroll
    for (int j = 0; j < 8; ++j) {
        int r = j * 2 + h;
        int node = nb + r;
        if (node < N_NODES) {
            float4 v  = *(const float4*)&Ew[r * 132 + c4];
            float4 xi = *(const float4*)(x + (size_t)node * D + c4);
            float4 o;
            o.x = fmaxf(v.x, 0.f) + xi.x;
            o.y = fmaxf(v.y, 0.f) + xi.y;
            o.z = fmaxf(v.z, 0.f) + xi.z;
            o.w = fmaxf(v.w, 0.f) + xi.w;
            *(float4*)(data + (size_t)node * D + c4) = o;
        }
    }
}

extern "C" void kernel_launch(void* const* d_in, const int* in_sizes, int n_in,
                              void* d_out, int out_size, void* d_ws, size_t ws_size,
                              hipStream_t stream) {
    const float* x   = (const float*)d_in[0];
    const int*   src = (const int*)d_in[1];   // harness passes integers as int32
    const int*   dst = (const int*)d_in[2];
    const float* W   = (const float*)d_in[3];
    float* out = (float*)d_out;

    char* ws = (char*)d_ws;
    int*    bcnt  = (int*)ws;        ws += (size_t)NBUCK * 4;
    ws = (char*)(((uintptr_t)ws + 15) & ~(uintptr_t)15);
    int*    pairs = (int*)ws;        ws += (size_t)NBUCK * BCAP * 4;
    ushort* xb    = (ushort*)ws;     ws += (size_t)N_NODES * D * 2;
    ushort* wb    = (ushort*)ws;     ws += (size_t)D * D * 2;
    const bool big_ws = (ws_size >= (size_t)(ws - (char*)d_ws));

    if (big_ws) {
        hipMemsetAsync(bcnt, 0, (size_t)NBUCK * 4, stream);    // 12.5 KB fill
        convert_scatter<<<CONV_BLOCKS, 256, 0, stream>>>(
            (const float4*)x, xb, W, wb, src, dst, bcnt, pairs);
        csr_gather_gemm<<<NBUCK, 256, 0, stream>>>(pairs, bcnt, xb, wb, out);
    } else {
        // slow-but-correct fallback (no scratch needed beyond d_out)
        int n4 = N_NODES * D / 4;
        zero_out<<<(n4 + 255) / 256, 256, 0, stream>>>((float4*)out, n4);
        long long n_scatter = (long long)N_EDGES * 32;
        scatter_edges<<<(int)((n_scatter + 255) / 256), 256, 0, stream>>>(
            x, src, dst, out);
        gemm_relu_res_f32<<<(N_NODES + 63) / 64, 256, 0, stream>>>(out, W, x);
    }
}

// Round 4
// 154.906 us; speedup vs baseline: 1.2601x; 1.2601x over previous
//
#include <hip/hip_runtime.h>
#include <hip/hip_bf16.h>

#define N_NODES 50000
#define N_EDGES 800000
#define D 128

#define NBUCK 3125       // bucket = dst>>4 (16 nodes); 50000 = 3125*16 exactly
#define NREP  4          // counter/segment replicas per bucket (blockIdx&3)
#define RCAP  192        // slots per (bucket,rep); lambda=64, +16 sigma
#define NMAX  768        // NREP*RCAP upper bound for lsrc sizing

#define CONV_BLOCKS 3200 // 819200 threads; edges: first 200000 threads x4

using bf16x8 = __attribute__((ext_vector_type(8))) short;   // 8 bf16 (4 VGPRs)
using u16x8  = __attribute__((ext_vector_type(8))) unsigned short;
using f32x4  = __attribute__((ext_vector_type(4))) float;   // MFMA C/D

static __device__ __forceinline__ ushort f2bf(float f) {
    __hip_bfloat16 h = __float2bfloat16(f);   // RNE
    return *reinterpret_cast<ushort*>(&h);
}
static __device__ __forceinline__ float bf2f(ushort u) {
    return __uint_as_float(((unsigned)u) << 16);
}

// ---------------------------------------------------------------------------
// ws layout (~23 MB): bcnt[NBUCK*NREP*16] int (64B-padded counters, 800 KB),
// pairs[NBUCK*NREP*RCAP] int (9.6 MB), xb (bf16 x, 12.8 MB), wb (bf16 W,
// chunk-major, 32 KB). Padding + 4-way replication caps atomic line
// serialization at ~64 updates/line (round-3 lesson: 16 counters/line x 4096
// updates/line = 60+ us of RMW serialization).
// ---------------------------------------------------------------------------

// Fused, sync-free: W->bf16 + edge scatter (padded/replicated atomics) + x->bf16.
__global__ void __launch_bounds__(256)
convert_scatter(const float4* __restrict__ x4, ushort* __restrict__ xb,
                const float* __restrict__ W, ushort* __restrict__ wb,
                const int* __restrict__ src, const int* __restrict__ dst,
                int* __restrict__ bcnt, int* __restrict__ pairs) {
    const int gt  = blockIdx.x * 256 + threadIdx.x;
    const int rep = blockIdx.x & (NREP - 1);

    // W -> bf16 chunk-major [k/8][o][8] (first 2048 threads)
    if (gt < 2048) {
        int o  = gt & 127;
        int kc = gt >> 7;
        const float4* wp = (const float4*)(W + (size_t)o * D + kc * 8);
        float4 w0 = wp[0], w1 = wp[1];
        bf16x8 hv;
        hv[0] = (short)f2bf(w0.x); hv[1] = (short)f2bf(w0.y);
        hv[2] = (short)f2bf(w0.z); hv[3] = (short)f2bf(w0.w);
        hv[4] = (short)f2bf(w1.x); hv[5] = (short)f2bf(w1.y);
        hv[6] = (short)f2bf(w1.z); hv[7] = (short)f2bf(w1.w);
        *(bf16x8*)&wb[gt * 8] = hv;
    }

    // edge scatter: 4 edges/thread via int4; padded counter = own 64B line
    if (gt < N_EDGES / 4) {
        int4 s = ((const int4*)src)[gt];
        int4 d = ((const int4*)dst)[gt];
#pragma unroll
        for (int e = 0; e < 4; ++e) {
            int sv = (e == 0) ? s.x : (e == 1) ? s.y : (e == 2) ? s.z : s.w;
            int dv = (e == 0) ? d.x : (e == 1) ? d.y : (e == 2) ? d.z : d.w;
            int seg = (dv >> 4) * NREP + rep;
            int pos = atomicAdd(&bcnt[seg * 16], 1);
            if (pos < RCAP)                       // 16-sd guard, never trips
                pairs[seg * RCAP + pos] = sv | ((dv & 15) << 16);
        }
    }

    // streaming conversion: 1.6M float4, <=2 iterations/thread
    const int total4 = N_NODES * D / 4;
    const int stride = CONV_BLOCKS * 256;
    for (int j = gt; j < total4; j += stride) {
        float4 v = x4[j];
        ushort4 u = make_ushort4(f2bf(v.x), f2bf(v.y), f2bf(v.z), f2bf(v.w));
        *(ushort4*)(xb + (size_t)j * 4) = u;
    }
}

// ---------------------------------------------------------------------------
// Fused per-bucket kernel: CSR-in-LDS (4 segments -> regs, single pass) ->
// gather with two-node interleave -> MFMA GEMM + relu + residual.
// One block per 16-node bucket, 256 threads (4 waves). LDS 14592 B.
// B-fragments from global wb (32 KB, L1-resident).
// ---------------------------------------------------------------------------
__global__ void __launch_bounds__(256)
csr_gather_gemm(const int* __restrict__ pairs, const int* __restrict__ bcnt,
                const ushort* __restrict__ xb, const ushort* __restrict__ wb,
                float* __restrict__ out) {
    __shared__ __align__(16) char lds[14592];
    ushort* lsrc  = (ushort*)lds;                    //  1600 B (784+ slots)
    ushort* aggL  = (ushort*)(lds + 1600);           //  4352 B [16][136]
    float*  Ew    = (float*)(lds + 5952);            //  8448 B [16][132]
    int*    lcnt2 = (int*)(lds + 14400);
    int*    lcur  = (int*)(lds + 14464);
    int*    lbeg  = (int*)(lds + 14528);

    const int b    = blockIdx.x;
    const int tid  = threadIdx.x;
    const int lane = tid & 63;
    const int wv   = tid >> 6;
    const int m16  = lane & 15;
    const int q    = lane >> 4;

    // ---- segment counts (broadcast scalar loads) ----
    const int pb = b * NREP;
    int c0 = bcnt[(pb + 0) * 16]; if (c0 > RCAP) c0 = RCAP;
    int c1 = bcnt[(pb + 1) * 16]; if (c1 > RCAP) c1 = RCAP;
    int c2 = bcnt[(pb + 2) * 16]; if (c2 > RCAP) c2 = RCAP;
    int c3 = bcnt[(pb + 3) * 16]; if (c3 > RCAP) c3 = RCAP;
    const int s1 = c0 + c1, s2 = s1 + c2, n = s2 + c3;   // n <= 768

    // ---- pairs -> regs (single global read), segment-resolved ----
    int p0 = -1, p1 = -1, p2 = -1;
#pragma unroll
    for (int k = 0; k < 3; ++k) {
        int i = tid + k * 256;
        if (i < n) {
            int rep, off;
            if      (i < c0) { rep = 0; off = i; }
            else if (i < s1) { rep = 1; off = i - c0; }
            else if (i < s2) { rep = 2; off = i - s1; }
            else             { rep = 3; off = i - s2; }
            int p = pairs[(pb + rep) * RCAP + off];
            if (k == 0) p0 = p; else if (k == 1) p1 = p; else p2 = p;
        }
    }

    // ---- CSR in LDS: histogram -> 16-lane scan -> place ----
    if (tid < 16) lcnt2[tid] = 0;
    __syncthreads();
    if (p0 >= 0) atomicAdd(&lcnt2[p0 >> 16], 1);
    if (p1 >= 0) atomicAdd(&lcnt2[p1 >> 16], 1);
    if (p2 >= 0) atomicAdd(&lcnt2[p2 >> 16], 1);
    __syncthreads();
    if (tid < 16) {                       // wave 0: 16-lane inclusive shfl scan
        int v = lcnt2[tid];
        int incl = v;
#pragma unroll
        for (int o = 1; o < 16; o <<= 1) {
            int t = __shfl_up(incl, o, 64);
            if (tid >= o) incl += t;
        }
        lbeg[tid] = incl - v;
        lcur[tid] = incl - v;
    }
    __syncthreads();
    if (p0 >= 0) { int pos = atomicAdd(&lcur[p0 >> 16], 1); lsrc[pos] = (ushort)(p0 & 0xFFFF); }
    if (p1 >= 0) { int pos = atomicAdd(&lcur[p1 >> 16], 1); lsrc[pos] = (ushort)(p1 & 0xFFFF); }
    if (p2 >= 0) { int pos = atomicAdd(&lcur[p2 >> 16], 1); lsrc[pos] = (ushort)(p2 & 0xFFFF); }
    __syncthreads();                      // lcur[t] == end(t) now

    // ---- gather: wave wv owns nodes wv*4..wv*4+3; two-node interleave ----
    // Quarter-wave rows: 16 lanes x u16x8 (16B) = one 256B bf16 row per load;
    // dual-node 8-row step = 4 outstanding loads (vs 1 in single-node path).
    const int c8 = m16 << 3;               // bf16 col 0,8,..,120
    const ushort* xbb = xb + c8;

    auto drain = [&](int t, int e, float* acc) {
        for (; t + 8 <= e; t += 8) {
            int s0 = lsrc[t + q];
            int s1v = lsrc[t + 4 + q];
            u16x8 u0 = *(const u16x8*)(xbb + (size_t)s0 * D);
            u16x8 u1 = *(const u16x8*)(xbb + (size_t)s1v * D);
#pragma unroll
            for (int j = 0; j < 8; ++j) acc[j] += bf2f(u0[j]) + bf2f(u1[j]);
        }
        for (; t + 4 <= e; t += 4) {
            int s = lsrc[t + q];
            u16x8 u = *(const u16x8*)(xbb + (size_t)s * D);
#pragma unroll
            for (int j = 0; j < 8; ++j) acc[j] += bf2f(u[j]);
        }
        const int rem = e - t;
        if (rem && q < rem) {
            int s = lsrc[t + q];
            u16x8 u = *(const u16x8*)(xbb + (size_t)s * D);
#pragma unroll
            for (int j = 0; j < 8; ++j) acc[j] += bf2f(u[j]);
        }
    };
    auto red_store = [&](int nloc, float* acc) {
#pragma unroll
        for (int j = 0; j < 8; ++j) {
            acc[j] += __shfl_xor(acc[j], 16, 64);
            acc[j] += __shfl_xor(acc[j], 32, 64);
        }
        if (q == 0) {                      // row write: 16 lanes x 16B, 256B
            u16x8 u;
#pragma unroll
            for (int j = 0; j < 8; ++j) u[j] = f2bf(acc[j]);
            *(u16x8*)&aggL[(size_t)nloc * 136 + c8] = u;
        }
    };

#pragma unroll 1
    for (int pm = 0; pm < 2; ++pm) {
        const int nA = wv * 4 + pm * 2;
        const int nB = nA + 1;
        int tA = lbeg[nA]; const int eA = lcur[nA];
        int tB = lbeg[nB]; const int eB = lcur[nB];
        float accA[8], accB[8];
#pragma unroll
        for (int j = 0; j < 8; ++j) { accA[j] = 0.f; accB[j] = 0.f; }

        // dual 8-row steps: 4 outstanding loads (wave-uniform control flow)
        while (tA + 8 <= eA && tB + 8 <= eB) {
            int a0 = lsrc[tA + q], a1 = lsrc[tA + 4 + q];
            int b0 = lsrc[tB + q], b1 = lsrc[tB + 4 + q];
            u16x8 uA0 = *(const u16x8*)(xbb + (size_t)a0 * D);
            u16x8 uA1 = *(const u16x8*)(xbb + (size_t)a1 * D);
            u16x8 uB0 = *(const u16x8*)(xbb + (size_t)b0 * D);
            u16x8 uB1 = *(const u16x8*)(xbb + (size_t)b1 * D);
#pragma unroll
            for (int j = 0; j < 8; ++j) {
                accA[j] += bf2f(uA0[j]) + bf2f(uA1[j]);
                accB[j] += bf2f(uB0[j]) + bf2f(uB1[j]);
            }
            tA += 8; tB += 8;
        }
        // dual 4-row steps: 2 outstanding
        while (tA + 4 <= eA && tB + 4 <= eB) {
            int a0 = lsrc[tA + q], b0 = lsrc[tB + q];
            u16x8 uA = *(const u16x8*)(xbb + (size_t)a0 * D);
            u16x8 uB = *(const u16x8*)(xbb + (size_t)b0 * D);
#pragma unroll
            for (int j = 0; j < 8; ++j) {
                accA[j] += bf2f(uA[j]);
                accB[j] += bf2f(uB[j]);
            }
            tA += 4; tB += 4;
        }
        drain(tA, eA, accA);
        drain(tB, eB, accB);
        red_store(nA, accA);
        red_store(nB, accB);
    }
    __syncthreads();                       // aggL complete

    // ---- MFMA GEMM: out[n][o] = relu(sum_k agg[n][k]*W[o][k]) + x[n][o] ----
    // All waves share the same 16 A-rows; wave wv computes cols wv*32..wv*32+31.
    bf16x8 a[4];
#pragma unroll
    for (int kb = 0; kb < 4; ++kb)
        a[kb] = *(const bf16x8*)&aggL[(size_t)m16 * 136 + kb * 32 + q * 8];

    f32x4 acc[2];
#pragma unroll
    for (int tt = 0; tt < 2; ++tt) {
        const int t = wv * 2 + tt;
        acc[tt] = (f32x4){0.f, 0.f, 0.f, 0.f};
#pragma unroll
        for (int kb = 0; kb < 4; ++kb) {
            bf16x8 bfr = *(const bf16x8*)&wb[(((kb * 4 + q) * 128) + t * 16 + m16) * 8];
            acc[tt] = __builtin_amdgcn_mfma_f32_16x16x32_bf16(a[kb], bfr, acc[tt], 0, 0, 0);
        }
    }

#pragma unroll
    for (int tt = 0; tt < 2; ++tt) {
        const int t = wv * 2 + tt;
#pragma unroll
        for (int r = 0; r < 4; ++r)
            Ew[(q * 4 + r) * 132 + t * 16 + m16] = acc[tt][r];
    }
    __syncthreads();                       // Ew complete (cross-wave cols)

    // ---- epilogue: relu + residual, 2 float4 per thread, coalesced ----
#pragma unroll
    for (int k = 0; k < 2; ++k) {
        int idx = tid + k * 256;
        int row = idx >> 5;                // 0..15
        int c4  = (idx & 31) << 2;         // f32 col 0,4,..,124
        int node = b * 16 + row;           // < 50000 always (3125*16 exact)
        float4 v  = *(const float4*)&Ew[row * 132 + c4];
        ushort4 xu = *(const ushort4*)(xb + (size_t)node * D + c4);
        float4 o;
        o.x = fmaxf(v.x, 0.f) + bf2f(xu.x);
        o.y = fmaxf(v.y, 0.f) + bf2f(xu.y);
        o.z = fmaxf(v.z, 0.f) + bf2f(xu.z);
        o.w = fmaxf(v.w, 0.f) + bf2f(xu.w);
        *(float4*)(out + (size_t)node * D + c4) = o;
    }
}

// ===================== minimal fallback (tiny ws; never expected) ==========
__global__ void zero_out(float4* __restrict__ p, int n4) {
    int i = blockIdx.x * 256 + threadIdx.x;
    if (i < n4) p[i] = make_float4(0.f, 0.f, 0.f, 0.f);
}
__global__ void scatter_edges(const float* __restrict__ x,
                              const int* __restrict__ src,
                              const int* __restrict__ dst,
                              float* __restrict__ agg) {
    long long tid = (long long)blockIdx.x * 256 + threadIdx.x;
    if (tid >= (long long)N_EDGES * 32) return;
    int edge = (int)(tid >> 5);
    int c    = ((int)tid & 31) << 2;
    const float4 v = *(const float4*)(x + (size_t)src[edge] * D + c);
    float* p = agg + (size_t)dst[edge] * D + c;
    unsafeAtomicAdd(p + 0, v.x);
    unsafeAtomicAdd(p + 1, v.y);
    unsafeAtomicAdd(p + 2, v.z);
    unsafeAtomicAdd(p + 3, v.w);
}
__global__ void __launch_bounds__(256)
gemm_relu_res_f32(float* data, const float* __restrict__ W,
                  const float* __restrict__ x) {
    __shared__ __align__(16) char lds[50176];
    ushort* Wl = (ushort*)lds;
    ushort* Al = (ushort*)(lds + 32768);
    const int tid  = threadIdx.x;
    const int lane = tid & 63;
    const int wv   = tid >> 6;
    const int m16  = lane & 15;
    const int q    = lane >> 4;
#pragma unroll
    for (int i = 0; i < 8; ++i) {
        int g  = tid + i * 256;
        int o  = g & 127;
        int kc = g >> 7;
        const float4* wp = (const float4*)(W + (size_t)o * D + kc * 8);
        float4 w0 = wp[0], w1 = wp[1];
        bf16x8 hv;
        hv[0] = (short)f2bf(w0.x); hv[1] = (short)f2bf(w0.y);
        hv[2] = (short)f2bf(w0.z); hv[3] = (short)f2bf(w0.w);
        hv[4] = (short)f2bf(w1.x); hv[5] = (short)f2bf(w1.y);
        hv[6] = (short)f2bf(w1.z); hv[7] = (short)f2bf(w1.w);
        *(bf16x8*)&Wl[g * 8] = hv;
    }
    __syncthreads();
    const int nb = blockIdx.x * 64 + wv * 16;
    ushort* Aw = &Al[wv * (16 * 136)];
#pragma unroll
    for (int m = 0; m < 16; ++m) {
        int node = nb + m;
        float2 v = make_float2(0.f, 0.f);
        if (node < N_NODES)
            v = *(const float2*)(data + (size_t)node * D + lane * 2);
        *(ushort2*)&Aw[m * 136 + lane * 2] = make_ushort2(f2bf(v.x), f2bf(v.y));
    }
    bf16x8 a[4];
#pragma unroll
    for (int kb = 0; kb < 4; ++kb)
        a[kb] = *(const bf16x8*)&Aw[m16 * 136 + kb * 32 + q * 8];
    f32x4 acc[8];
#pragma unroll
    for (int t = 0; t < 8; ++t) {
        acc[t] = (f32x4){0.f, 0.f, 0.f, 0.f};
#pragma unroll
        for (int kb = 0; kb < 4; ++kb) {
            bf16x8 bfr = *(const bf16x8*)&Wl[(((kb * 4 + q) * 128) + t * 16 + m16) * 8];
            acc[t] = __builtin_amdgcn_mfma_f32_16x16x32_bf16(a[kb], bfr, acc[t], 0, 0, 0);
        }
    }
    __syncthreads();
    float* Ew = (float*)(lds + wv * 8448);
#pragma unroll
    for (int t = 0; t < 8; ++t)
#pragma unroll
        for (int r = 0; r < 4; ++r)
            Ew[(q * 4 + r) * 132 + t * 16 + m16] = acc[t][r];
    const int h  = lane >> 5;
    const int c4 = (lane & 31) << 2;
#pragma unroll
    for (int j = 0; j < 8; ++j) {
        int r = j * 2 + h;
        int node = nb + r;
        if (node < N_NODES) {
            float4 v  = *(const float4*)&Ew[r * 132 + c4];
            float4 xi = *(const float4*)(x + (size_t)node * D + c4);
            float4 o;
            o.x = fmaxf(v.x, 0.f) + xi.x;
            o.y = fmaxf(v.y, 0.f) + xi.y;
            o.z = fmaxf(v.z, 0.f) + xi.z;
            o.w = fmaxf(v.w, 0.f) + xi.w;
            *(float4*)(data + (size_t)node * D + c4) = o;
        }
    }
}

extern "C" void kernel_launch(void* const* d_in, const int* in_sizes, int n_in,
                              void* d_out, int out_size, void* d_ws, size_t ws_size,
                              hipStream_t stream) {
    const float* x   = (const float*)d_in[0];
    const int*   src = (const int*)d_in[1];   // harness passes integers as int32
    const int*   dst = (const int*)d_in[2];
    const float* W   = (const float*)d_in[3];
    float* out = (float*)d_out;

    char* ws = (char*)d_ws;
    int*    bcnt  = (int*)ws;        ws += (size_t)NBUCK * NREP * 64;
    int*    pairs = (int*)ws;        ws += (size_t)NBUCK * NREP * RCAP * 4;
    ushort* xb    = (ushort*)ws;     ws += (size_t)N_NODES * D * 2;
    ushort* wb    = (ushort*)ws;     ws += (size_t)D * D * 2;
    const bool big_ws = (ws_size >= (size_t)(ws - (char*)d_ws));

    if (big_ws) {
        hipMemsetAsync(bcnt, 0, (size_t)NBUCK * NREP * 64, stream);  // 800 KB
        convert_scatter<<<CONV_BLOCKS, 256, 0, stream>>>(
            (const float4*)x, xb, W, wb, src, dst, bcnt, pairs);
        csr_gather_gemm<<<NBUCK, 256, 0, stream>>>(pairs, bcnt, xb, wb, out);
    } else {
        // slow-but-correct fallback (no scratch needed beyond d_out)
        int n4 = N_NODES * D / 4;
        zero_out<<<(n4 + 255) / 256, 256, 0, stream>>>((float4*)out, n4);
        long long n_scatter = (long long)N_EDGES * 32;
        scatter_edges<<<(int)((n_scatter + 255) / 256), 256, 0, stream>>>(
            x, src, dst, out);
        gemm_relu_res_f32<<<(N_NODES + 63) / 64, 256, 0, stream>>>(out, W, x);
    }
}